// Round 4
// baseline (504.435 us; speedup 1.0000x reference)
//
#include <hip/hip_runtime.h>

#define NT 512   // T
#define NB 128   // B
#define ND 256   // D
#define NH 256   // H

typedef _Float16 h2 __attribute__((ext_vector_type(2)));

#if __has_builtin(__builtin_amdgcn_fdot2)
#define DOT2(a, b, c) __builtin_amdgcn_fdot2((a), (b), (c), false)
#else
#define DOT2(a, b, c) (fmaf((float)(a).x, (float)(b).x, \
                        fmaf((float)(a).y, (float)(b).y, (c))))
#endif

// value-level keep-alive: never takes an address, so the array stays in VGPRs
#define PIN32(x) do {                               \
    float _f = __builtin_bit_cast(float, (x));      \
    asm volatile("" : "+v"(_f));                    \
    (x) = __builtin_bit_cast(h2, _f);               \
} while (0)

// ---------------------------------------------------------------------------
// Phase 1: Z = X @ Wi^T + bh.  Register-tiled fp32 GEMM (unchanged).
// ---------------------------------------------------------------------------
__global__ __launch_bounds__(256) void zprep_kernel(
    const float* __restrict__ X, const float* __restrict__ Wi,
    const float* __restrict__ bh, float* __restrict__ Z)
{
    __shared__ float xsT[64][68];   // [k][m]
    __shared__ float wsT[64][68];   // [k][j]
    const int tid = threadIdx.x;
    const int tm  = tid & 15, tj = tid >> 4;
    const int m0  = blockIdx.x * 64;
    const int j0  = blockIdx.y * 64;
    const int sm  = tid >> 2, kq = tid & 3;

    float acc[4][4] = {};

    for (int c = 0; c < 4; ++c) {
        const int k0 = c * 64;
        const float* xr = X  + (size_t)(m0 + sm) * ND + k0 + kq * 16;
        const float* wr = Wi + (size_t)(j0 + sm) * ND + k0 + kq * 16;
        #pragma unroll
        for (int i = 0; i < 4; ++i) {
            const float4 xv = *(const float4*)(xr + i * 4);
            const float4 wv = *(const float4*)(wr + i * 4);
            const int kk = kq * 16 + i * 4;
            xsT[kk + 0][sm] = xv.x; xsT[kk + 1][sm] = xv.y;
            xsT[kk + 2][sm] = xv.z; xsT[kk + 3][sm] = xv.w;
            wsT[kk + 0][sm] = wv.x; wsT[kk + 1][sm] = wv.y;
            wsT[kk + 2][sm] = wv.z; wsT[kk + 3][sm] = wv.w;
        }
        __syncthreads();

        #pragma unroll 8
        for (int k = 0; k < 64; ++k) {
            const float4 x4 = *(const float4*)&xsT[k][tm * 4];
            const float4 w4 = *(const float4*)&wsT[k][tj * 4];
            acc[0][0] = fmaf(x4.x, w4.x, acc[0][0]);
            acc[0][1] = fmaf(x4.x, w4.y, acc[0][1]);
            acc[0][2] = fmaf(x4.x, w4.z, acc[0][2]);
            acc[0][3] = fmaf(x4.x, w4.w, acc[0][3]);
            acc[1][0] = fmaf(x4.y, w4.x, acc[1][0]);
            acc[1][1] = fmaf(x4.y, w4.y, acc[1][1]);
            acc[1][2] = fmaf(x4.y, w4.z, acc[1][2]);
            acc[1][3] = fmaf(x4.y, w4.w, acc[1][3]);
            acc[2][0] = fmaf(x4.z, w4.x, acc[2][0]);
            acc[2][1] = fmaf(x4.z, w4.y, acc[2][1]);
            acc[2][2] = fmaf(x4.z, w4.z, acc[2][2]);
            acc[2][3] = fmaf(x4.z, w4.w, acc[2][3]);
            acc[3][0] = fmaf(x4.w, w4.x, acc[3][0]);
            acc[3][1] = fmaf(x4.w, w4.y, acc[3][1]);
            acc[3][2] = fmaf(x4.w, w4.z, acc[3][2]);
            acc[3][3] = fmaf(x4.w, w4.w, acc[3][3]);
        }
        __syncthreads();
    }

    const float4 b4 = *(const float4*)&bh[j0 + tj * 4];
    #pragma unroll
    for (int r = 0; r < 4; ++r) {
        float4 o;
        o.x = acc[r][0] + b4.x; o.y = acc[r][1] + b4.y;
        o.z = acc[r][2] + b4.z; o.w = acc[r][3] + b4.w;
        *(float4*)&Z[(size_t)(m0 + tm * 4 + r) * NH + j0 + tj * 4] = o;
    }
}

// ---------------------------------------------------------------------------
// Phase 2: recurrence, fp16 dot2 / fp32 accumulate.
// One WG / batch row, 512 threads. ks=tid&3 owns a 64-wide k-slice of
// outputs j0=2jb, 2jb+1 (jb=tid>>2). 64 half2 weight VGPRs per thread,
// pinned with value-level bit_cast asm (NO address taken).
// h double-buffered in LDS (slice ks at dword ks*36 -> conflict-free
// broadcast b128). Global h-store deferred past the barrier (vmcnt drain
// before s_barrier would otherwise serialize the store-ack every step).
// ---------------------------------------------------------------------------
__global__ __launch_bounds__(512, 2) void rnn_step_kernel(
    float* __restrict__ ZO,
    const float* __restrict__ h0,
    const float* __restrict__ Wh)
{
    __shared__ h2 hb[2][4 * 36];
    const int b   = blockIdx.x;
    const int tid = threadIdx.x;
    const int ks  = tid & 3;
    const int jb  = tid >> 2;
    const int j0  = jb * 2;

    // Wh rows j0, j0+1, k-slice [ks*64, ks*64+64) -> 32+32 packed half2 regs
    h2 w0p[32], w1p[32];
    {
        const float* r0 = Wh + (size_t)j0 * NH + ks * 64;
        const float* r1 = r0 + NH;
        #pragma unroll
        for (int i = 0; i < 16; ++i) {
            const float4 a = *(const float4*)(r0 + 4 * i);
            const float4 c = *(const float4*)(r1 + 4 * i);
            w0p[2*i+0] = h2{(_Float16)a.x, (_Float16)a.y};
            w0p[2*i+1] = h2{(_Float16)a.z, (_Float16)a.w};
            w1p[2*i+0] = h2{(_Float16)c.x, (_Float16)c.y};
            w1p[2*i+1] = h2{(_Float16)c.z, (_Float16)c.w};
        }
    }
    #pragma unroll
    for (int i = 0; i < 32; ++i) { PIN32(w0p[i]); PIN32(w1p[i]); }

    if (tid < 128) {
        const float2 hp = *(const float2*)(h0 + (size_t)b * NH + tid * 2);
        hb[0][(tid >> 5) * 36 + (tid & 31)] =
            h2{(_Float16)hp.x, (_Float16)hp.y};
    }

    float2 z2 = make_float2(0.f, 0.f);
    if (ks == 0) z2 = *(const float2*)(ZO + (size_t)b * NH + j0);   // t = 0
    float2 hprev = make_float2(0.f, 0.f);
    __syncthreads();

    int cur = 0;
    for (int t = 0; t < NT; ++t) {
        // read this thread's 32 half2 of h (8 x ds_read_b128) — issue first
        h2 hh[32];
        const h2* hv = &hb[cur][ks * 36];
        #pragma unroll
        for (int i = 0; i < 8; ++i)
            *(float4*)&hh[4 * i] = *(const float4*)&hv[4 * i];

        // deferred global store of step t-1's hidden (overlaps this step)
        if (t > 0 && ks == 0)
            *(float2*)(ZO + ((size_t)(t - 1) * NB + b) * NH + j0) = hprev;

        // prefetch z for t+1 early so it overlaps the dot
        float2 z2n = z2;
        if (t + 1 < NT && ks == 0)
            z2n = *(const float2*)(ZO + ((size_t)(t + 1) * NB + b) * NH + j0);

        float a0 = 0.f, a1 = 0.f, c0 = 0.f, c1 = 0.f;
        #pragma unroll
        for (int i = 0; i < 16; ++i) {
            a0 = DOT2(w0p[i],      hh[i],      a0);
            a1 = DOT2(w1p[i],      hh[i],      a1);
            c0 = DOT2(w0p[i + 16], hh[i + 16], c0);
            c1 = DOT2(w1p[i + 16], hh[i + 16], c1);
        }
        float s0 = a0 + c0;
        float s1 = a1 + c1;

        s0 += __shfl_xor(s0, 1); s1 += __shfl_xor(s1, 1);
        s0 += __shfl_xor(s0, 2); s1 += __shfl_xor(s1, 2);

        if (ks == 0) {
            const float p0 = z2.x + s0;
            const float p1 = z2.y + s1;
            const float hn0 = 1.0f / (1.0f + __expf(-p0));
            const float hn1 = 1.0f / (1.0f + __expf(-p1));
            hb[cur ^ 1][(jb >> 5) * 36 + (jb & 31)] =
                h2{(_Float16)hn0, (_Float16)hn1};
            hprev = make_float2(hn0, hn1);
        }
        z2 = z2n;
        __syncthreads();
        cur ^= 1;
    }
    if (ks == 0)
        *(float2*)(ZO + ((size_t)(NT - 1) * NB + b) * NH + j0) = hprev;
}

extern "C" void kernel_launch(void* const* d_in, const int* in_sizes, int n_in,
                              void* d_out, int out_size, void* d_ws, size_t ws_size,
                              hipStream_t stream) {
    const float* X  = (const float*)d_in[0];
    const float* h0 = (const float*)d_in[1];
    const float* Wi = (const float*)d_in[2];
    const float* Wh = (const float*)d_in[3];
    const float* bh = (const float*)d_in[4];
    float* out = (float*)d_out;

    dim3 zgrid((NT * NB) / 64, NH / 64);
    zprep_kernel<<<zgrid, 256, 0, stream>>>(X, Wi, bh, out);
    rnn_step_kernel<<<NB, 512, 0, stream>>>(out, h0, Wh);
}